// Round 3
// baseline (568.102 us; speedup 1.0000x reference)
//
#include <hip/hip_runtime.h>
#include <cmath>

#define T_SEQ 2048
#define NH    16
#define HD    64
#define DM    1024
#define BATCH 4

typedef __attribute__((ext_vector_type(8))) short bf16x8;
typedef __attribute__((ext_vector_type(4))) float f32x4;
typedef unsigned short ushort_t;

__device__ __forceinline__ unsigned short f2bf(float x) {   // rne fp32->bf16
    union { float f; unsigned u; } v; v.f = x;
    unsigned r = v.u + 0x7fffu + ((v.u >> 16) & 1u);
    return (unsigned short)(r >> 16);
}
__device__ __forceinline__ float bf2f(unsigned short h) {
    union { unsigned u; float f; } v; v.u = ((unsigned)h) << 16;
    return v.f;
}
__device__ __forceinline__ unsigned fbits(float x) {
    union { float f; unsigned u; } v; v.f = x; return v.u;
}
__device__ __forceinline__ float bitsf(unsigned x) {
    union { unsigned u; float f; } v; v.u = x; return v.f;
}
// raw v_exp_f32 (2^x) — __exp2f doesn't exist on this ROCm (R10 compile fail)
__device__ __forceinline__ float exp2_raw(float x) {
    return __builtin_amdgcn_exp2f(x);
}
// packed fp32x2 -> bf16x2 (RNE), one instruction (R1-verified)
__device__ __forceinline__ unsigned cvtpk_bf16(float a, float b) {
    unsigned r;
    asm("v_cvt_pk_bf16_f32 %0, %1, %2" : "=v"(r) : "v"(a), "v"(b));
    return r;
}

// async global->LDS DMA, 16 B per lane (verified R7/R9).
__device__ __forceinline__ void dma16(const void* g, const void* l) {
    __builtin_amdgcn_global_load_lds(
        (const __attribute__((address_space(1))) unsigned int*)(unsigned long long)g,
        (__attribute__((address_space(3))) unsigned int*)(unsigned int)(unsigned long long)l,
        16, 0, 0);
}

// -------------------------------------------------------------------------
// Kernel 1: mask prep. Emits ADDITIVE bias: 0.0 (attend) / -1e30 (pad).
// -------------------------------------------------------------------------
__global__ void maskprep_kernel(const int* __restrict__ pad, float* __restrict__ valid)
{
    __shared__ int sall[256];
    const int b = blockIdx.x;
    const int t = threadIdx.x;
    int allp = 1;
    for (int i = t; i < T_SEQ; i += 256) allp &= (pad[b*T_SEQ + i] != 0) ? 1 : 0;
    sall[t] = allp;
    __syncthreads();
    for (int s = 128; s > 0; s >>= 1) {
        if (t < s) sall[t] &= sall[t + s];
        __syncthreads();
    }
    const int ap = sall[0];
    for (int i = t; i < T_SEQ; i += 256) {
        const int p = (pad[b*T_SEQ + i] != 0) ? 1 : 0;
        valid[b*T_SEQ + i] = (p && !ap) ? -1e30f : 0.0f;
    }
}

// -------------------------------------------------------------------------
// Kernel 2: weight transpose+split (unchanged). W[K][N] -> Th/Tl[N][K].
// -------------------------------------------------------------------------
__global__ __launch_bounds__(256)
void transpose_split_kernel(const float* __restrict__ W,
                            ushort_t* __restrict__ Th, ushort_t* __restrict__ Tl,
                            int K, int N)
{
    __shared__ float T[64][68];
    const int tid = threadIdx.x;
    const int n0 = blockIdx.x * 64;
    const int k0 = blockIdx.y * 64;
#pragma unroll
    for (int i = 0; i < 4; ++i) {
        const int kr = (tid >> 4) + i*16;
        const int nc = (tid & 15) * 4;
        const float4 v = *(const float4*)&W[(size_t)(k0 + kr)*N + n0 + nc];
        T[nc+0][kr] = v.x; T[nc+1][kr] = v.y; T[nc+2][kr] = v.z; T[nc+3][kr] = v.w;
    }
    __syncthreads();
#pragma unroll
    for (int i = 0; i < 4; ++i) {
        const int nr = (tid >> 4) + i*16;
        const int kc = (tid & 15) * 4;
        ushort_t h[4], l[4];
#pragma unroll
        for (int j = 0; j < 4; ++j) {
            const float x = T[nr][kc + j];
            h[j] = f2bf(x);
            l[j] = f2bf(x - bf2f(h[j]));
        }
        const size_t off = (size_t)(n0 + nr)*K + k0 + kc;
        *(short4*)&Th[off] = make_short4(h[0], h[1], h[2], h[3]);
        *(short4*)&Tl[off] = make_short4(l[0], l[1], l[2], l[3]);
    }
}

// -------------------------------------------------------------------------
// Kernel 2b: row-major fp32 -> bf16 hi/lo split (tokens only now).
// -------------------------------------------------------------------------
__global__ __launch_bounds__(256)
void split_kernel(const float* __restrict__ X,
                  ushort_t* __restrict__ H, ushort_t* __restrict__ L)
{
    const int i = blockIdx.x * 256 + threadIdx.x;     // float4 index
    const float4 v = ((const float4*)X)[i];
    const float x[4] = {v.x, v.y, v.z, v.w};
    ushort_t h[4], l[4];
#pragma unroll
    for (int j = 0; j < 4; ++j) {
        const unsigned u = fbits(x[j]);
        h[j] = (ushort_t)(u >> 16);
        l[j] = f2bf(x[j] - bitsf(u & 0xffff0000u));
    }
    *(short4*)&H[(size_t)i*4] = make_short4(h[0], h[1], h[2], h[3]);
    *(short4*)&L[(size_t)i*4] = make_short4(l[0], l[1], l[2], l[3]);
}

// -------------------------------------------------------------------------
// Kernel 3/5: split-bf16 MFMA GEMM (R9 structure, verified no-spill).
// 64x128xBK32 block tile, 32x64 wave tile. Q scale 0.125*log2(e) so
// attention softmax runs in exp2 domain.
// -------------------------------------------------------------------------
template<int EPI>
__global__ __launch_bounds__(256)
void mfma_gemm_kernel(const ushort_t* __restrict__ Ath, const ushort_t* __restrict__ Atl,
                      const ushort_t* __restrict__ BTh, const ushort_t* __restrict__ BTl,
                      const float* __restrict__ bias,
                      float* __restrict__ O0,
                      ushort_t* __restrict__ Qhi, ushort_t* __restrict__ Qlo,
                      ushort_t* __restrict__ Khi, ushort_t* __restrict__ Klo,
                      ushort_t* __restrict__ Vthi, ushort_t* __restrict__ Vtlo,
                      int M, int N, int K)
{
    __shared__ __align__(16) char smem[34816];
    char* smAh = smem;             // [64][32] bf16 = 4 KB
    char* smAl = smem + 4096;
    char* smBh = smem + 8192;      // [128][32] bf16 = 8 KB
    char* smBl = smem + 16384;

    const int tid  = threadIdx.x;
    const int w    = tid >> 6;
    const int ln   = tid & 63;
    const int lx   = ln & 15;
    const int quad = ln >> 4;
    const int mw   = (w >> 1) * 32;
    const int nw   = (w & 1) * 64;
    const int m0   = blockIdx.y * 64;
    const int n0   = blockIdx.x * 128;

    const size_t gaA = (size_t)(m0 + w*16 + (ln >> 2))*K + (ln & 3)*8;
    const size_t gaB = (size_t)(n0 + w*32 + (ln >> 2))*K + (ln & 3)*8;
    const int ldsA = (w*64 + ln)*16;
    const int ldsB = (w*128 + ln)*16;

#define ISSUE_DMA(kk) do {                                               \
        dma16(Ath + gaA + (kk),        smAh + ldsA);                     \
        dma16(Atl + gaA + (kk),        smAl + ldsA);                     \
        dma16(BTh + gaB + (kk),        smBh + ldsB);                     \
        dma16(BTh + gaB + 16*K + (kk), smBh + ldsB + 1024);              \
        dma16(BTl + gaB + (kk),        smBl + ldsB);                     \
        dma16(BTl + gaB + 16*K + (kk), smBl + ldsB + 1024);              \
    } while (0)

    f32x4 acc[2][4];
#pragma unroll
    for (int mt = 0; mt < 2; ++mt)
#pragma unroll
        for (int nt = 0; nt < 4; ++nt) acc[mt][nt] = (f32x4){0.f,0.f,0.f,0.f};

    ISSUE_DMA(0);

    for (int kk = 0; kk < K; kk += 32) {
        __syncthreads();

        bf16x8 bfh[4], bfl[4];
#pragma unroll
        for (int nt = 0; nt < 4; ++nt) {
            const int off = (nw + nt*16 + lx)*64 + quad*16;
            bfh[nt] = *(const bf16x8*)(smBh + off);
            bfl[nt] = *(const bf16x8*)(smBl + off);
        }
        bf16x8 afh0, afl0, afh1, afl1;
        {
            const int o0 = (mw + lx)*64 + quad*16;
            const int o1 = (mw + 16 + lx)*64 + quad*16;
            afh0 = *(const bf16x8*)(smAh + o0);
            afl0 = *(const bf16x8*)(smAl + o0);
            afh1 = *(const bf16x8*)(smAh + o1);
            afl1 = *(const bf16x8*)(smAl + o1);
        }
        __syncthreads();
        if (kk + 32 < K) ISSUE_DMA(kk + 32);

        __builtin_amdgcn_s_setprio(1);
#pragma unroll
        for (int nt = 0; nt < 4; ++nt) {
            acc[0][nt] = __builtin_amdgcn_mfma_f32_16x16x32_bf16(afh0, bfh[nt], acc[0][nt], 0, 0, 0);
            acc[0][nt] = __builtin_amdgcn_mfma_f32_16x16x32_bf16(afh0, bfl[nt], acc[0][nt], 0, 0, 0);
            acc[0][nt] = __builtin_amdgcn_mfma_f32_16x16x32_bf16(afl0, bfh[nt], acc[0][nt], 0, 0, 0);
        }
#pragma unroll
        for (int nt = 0; nt < 4; ++nt) {
            acc[1][nt] = __builtin_amdgcn_mfma_f32_16x16x32_bf16(afh1, bfh[nt], acc[1][nt], 0, 0, 0);
            acc[1][nt] = __builtin_amdgcn_mfma_f32_16x16x32_bf16(afh1, bfl[nt], acc[1][nt], 0, 0, 0);
            acc[1][nt] = __builtin_amdgcn_mfma_f32_16x16x32_bf16(afl1, bfh[nt], acc[1][nt], 0, 0, 0);
        }
        __builtin_amdgcn_s_setprio(0);
    }
#undef ISSUE_DMA

    // ---------------- epilogue ----------------
    if (EPI == 0) {
#pragma unroll
        for (int nt = 0; nt < 4; ++nt) {
            const int n = n0 + nw + nt*16 + lx;
#pragma unroll
            for (int mt = 0; mt < 2; ++mt)
#pragma unroll
                for (int r = 0; r < 4; ++r) {
                    const int m = m0 + mw + mt*16 + quad*4 + r;
                    O0[(size_t)m*N + n] = acc[mt][nt][r] + bias[n];
                }
        }
    } else {
        const int which = n0 >> 10;           // block-uniform: 0=q 1=k 2=v
        const int hbase = (n0 & 1023) >> 6;
        const int b     = m0 >> 11;
        const int t0    = m0 & 2047;
        float* Ct = (float*)smem;             // Q/K: [64][132]; V: [128][68]
        const float ssign = (lx & 1) ? 1.0f : -1.0f;

        __syncthreads();
        if (which < 2) {
#pragma unroll
            for (int nt = 0; nt < 4; ++nt) {
                const int nl = nw + nt*16 + lx;
                const int d  = nl & 63;
                const float bn = bias[n0 + nl];
                const float freq = expf(-(float)(d >> 1) * 0.28782313662425575f);
#pragma unroll
                for (int mt = 0; mt < 2; ++mt)
#pragma unroll
                    for (int r = 0; r < 4; ++r) {
                        const int ml = mw + mt*16 + quad*4 + r;
                        const int t  = t0 + ml;
                        float res = acc[mt][nt][r] + bn;
                        const float ang = (float)t * freq;
                        const float sn = sinf(ang), cs = cosf(ang);
                        const float prt = __shfl_xor(res, 1);
                        res = res*cs + ssign*prt*sn;
                        // Q scale folds 1/sqrt(hd) AND log2(e): softmax in exp2 domain
                        if (which == 0) res *= 0.18033688011112042f;
                        Ct[ml*132 + nl] = res;
                    }
            }
        } else {
#pragma unroll
            for (int nt = 0; nt < 4; ++nt) {
                const int nl = nw + nt*16 + lx;
                const float bn = bias[n0 + nl];
#pragma unroll
                for (int mt = 0; mt < 2; ++mt)
#pragma unroll
                    for (int r = 0; r < 4; ++r) {
                        const int ml = mw + mt*16 + quad*4 + r;
                        Ct[nl*68 + ml] = acc[mt][nt][r] + bn;
                    }
            }
        }
        __syncthreads();

        if (which < 2) {
            ushort_t* dH = which ? Khi : Qhi;
            ushort_t* dL = which ? Klo : Qlo;
#pragma unroll
            for (int u = 0; u < 4; ++u) {
                const int L  = u*32 + (tid >> 3);
                const int t  = L & 63;
                const int hl = L >> 6;
                const int dg = (tid & 7) * 8;
                const float* src = &Ct[t*132 + hl*64 + dg];
                float v[8];
                *(f32x4*)&v[0] = *(const f32x4*)src;
                *(f32x4*)&v[4] = *(const f32x4*)(src + 4);
                bf16x8 h8, l8;
#pragma unroll
                for (int j = 0; j < 8; ++j) {
                    const unsigned u32 = fbits(v[j]);
                    h8[j] = (short)(u32 >> 16);
                    l8[j] = (short)f2bf(v[j] - bitsf(u32 & 0xffff0000u));
                }
                const int bh = b*NH + hbase + hl;
                const size_t off = (((size_t)bh)*T_SEQ + t0 + t)*64 + dg;
                *(bf16x8*)&dH[off] = h8;
                *(bf16x8*)&dL[off] = l8;
            }
        } else {
#pragma unroll
            for (int u = 0; u < 4; ++u) {
                const int row = u*32 + (tid >> 3);
                const int d   = row & 63;
                const int hl  = row >> 6;
                const int tg  = (tid & 7) * 8;
                const float* src = &Ct[row*68 + tg];
                float v[8];
                *(f32x4*)&v[0] = *(const f32x4*)src;
                *(f32x4*)&v[4] = *(const f32x4*)(src + 4);
                bf16x8 h8, l8;
#pragma unroll
                for (int j = 0; j < 8; ++j) {
                    const unsigned u32 = fbits(v[j]);
                    h8[j] = (short)(u32 >> 16);
                    l8[j] = (short)f2bf(v[j] - bitsf(u32 & 0xffff0000u));
                }
                const int bh = b*NH + hbase + hl;
                const size_t off = (((size_t)bh)*HD + d)*T_SEQ + t0 + tg;
                *(bf16x8*)&Vthi[off] = h8;
                *(bf16x8*)&Vtlo[off] = l8;
            }
        }
    }
}

// -------------------------------------------------------------------------
// Kernel 4: flash attention, swapped-QK^T formulation (R1 layout).
// R3: mask folded into MFMA C-in, defer-max (THR=8, T13), s_setprio (T5).
// v_pk_* inline asm REMOVED (R2 fail suspect: VOP3P op_sel_hi assembler
// default → hi lane duplicated lo lane); plain scalar f32 ops instead.
// max3 via nested fmaxf (compiler fuses to v_max3_f32).
// -------------------------------------------------------------------------
__global__ __launch_bounds__(512, 4)
void attn_mfma_kernel(const ushort_t* __restrict__ Qhi, const ushort_t* __restrict__ Qlo,
                      const ushort_t* __restrict__ Khi, const ushort_t* __restrict__ Klo,
                      const ushort_t* __restrict__ Vthi, const ushort_t* __restrict__ Vtlo,
                      const float* __restrict__ mbias,
                      ushort_t* __restrict__ AOh, ushort_t* __restrict__ AOl)
{
    __shared__ ushort_t KH[64*64];
    __shared__ ushort_t KL[64*64];
    __shared__ ushort_t VH[64*64];
    __shared__ ushort_t VL[64*64];

    const int tid  = threadIdx.x;
    const int w    = tid >> 6;          // 0..7
    const int ln   = tid & 63;
    const int lx   = ln & 15;
    const int quad = ln >> 4;

    // 1024 blocks: id&7 = bh low bits (XCD), (id>>3)&15 = qt, id>>7 = bh hi
    const int id = blockIdx.x;
    const int qt = (id >> 3) & 15;
    const int bh = ((id >> 7) << 3) | (id & 7);
    const int b  = bh >> 4;
    const int h  = bh & 15;
    const int qrow0 = qt*128 + w*16;

    // Q fragments (B operand)
    bf16x8 qh[2], ql[2];
    {
        const size_t qoff = (((size_t)bh)*T_SEQ + qrow0 + lx)*HD + quad*8;
        qh[0] = *(const bf16x8*)&Qhi[qoff];
        qh[1] = *(const bf16x8*)&Qhi[qoff + 32];
        ql[0] = *(const bf16x8*)&Qlo[qoff];
        ql[1] = *(const bf16x8*)&Qlo[qoff + 32];
    }

    // staging: wave w stages rows [w*8, w*8+8); lane ln -> row w*8+(ln>>3),
    // chunk ln&7; swizzled store pos = sch ^ g(srow).
    const int srow = w*8 + (ln >> 3);
    const int sch  = ln & 7;
    const size_t kg0 = ((size_t)bh*T_SEQ + srow)*HD + sch*8;
    const size_t vg0 = ((size_t)bh*HD + srow)*T_SEQ + sch*8;
    const int gs = ((ln >> 3) & 3) ^ ((w & 1) << 2);
    const int lw = srow*64 + ((sch ^ gs) << 3);

    // K A-fragment read base: row(nt=0) = 8*(lx>>2)+(lx&3); g(row) == lx&7
    const int r0  = ((lx >> 2) << 3) + (lx & 3);
    const int ka0 = r0*64 + ((quad ^ (lx & 7)) << 3);
    // V B-fragment read base: row = nt*16+lx; g(row) == gv
    const int gv  = (lx & 3) ^ (((lx >> 3) & 1) << 2);
    const int va0 = lx*64 + ((quad ^ gv) << 3);

    // additive mask bias, float4 per (nt): k = kt*64 +32*(nt>>1)+8*quad+4*(nt&1)+r
    const float* mrow = mbias + (size_t)b*T_SEQ + (quad << 3);

    f32x4 o[4];
#pragma unroll
    for (int nt = 0; nt < 4; ++nt) o[nt] = (f32x4){0.f, 0.f, 0.f, 0.f};
    float mrun = -INFINITY;
    float lrun = 0.f;

    bf16x8 rkh, rkl, rvh, rvl;
    rkh = *(const bf16x8*)&Khi [kg0];
    rkl = *(const bf16x8*)&Klo [kg0];
    rvh = *(const bf16x8*)&Vthi[vg0];
    rvl = *(const bf16x8*)&Vtlo[vg0];
    *(bf16x8*)&KH[lw] = rkh;
    *(bf16x8*)&KL[lw] = rkl;
    *(bf16x8*)&VH[lw] = rvh;
    *(bf16x8*)&VL[lw] = rvl;
    __syncthreads();

    for (int kt = 0; kt < T_SEQ/64; ++kt) {
        const int ktn = (kt+1 < T_SEQ/64) ? kt+1 : kt;
        rkh = *(const bf16x8*)&Khi [kg0 + (size_t)ktn*64*HD];
        rkl = *(const bf16x8*)&Klo [kg0 + (size_t)ktn*64*HD];
        rvh = *(const bf16x8*)&Vthi[vg0 + ktn*64];
        rvl = *(const bf16x8*)&Vtlo[vg0 + ktn*64];

        // ---- QK^T (K is the A operand; mask bias preloaded as C-in) ----
        f32x4 s[4];
        __builtin_amdgcn_s_setprio(1);
#pragma unroll
        for (int nt = 0; nt < 4; ++nt) {
            const int a0 = ka0 + ((nt & 1) << 8) + ((nt >> 1) << 11);
            const bf16x8 kh0 = *(const bf16x8*)&KH[a0];
            const bf16x8 kh1 = *(const bf16x8*)&KH[a0 ^ 32];
            const bf16x8 kl0 = *(const bf16x8*)&KL[a0];
            const bf16x8 kl1 = *(const bf16x8*)&KL[a0 ^ 32];
            // mask bias as accumulator seed (replaces zero-init + 16 adds)
            s[nt] = *(const f32x4*)&mrow[kt*64 + ((nt >> 1) << 5) + ((nt & 1) << 2)];
            s[nt] = __builtin_amdgcn_mfma_f32_16x16x32_bf16(kh0, qh[0], s[nt], 0, 0, 0);
            s[nt] = __builtin_amdgcn_mfma_f32_16x16x32_bf16(kh1, qh[1], s[nt], 0, 0, 0);
            s[nt] = __builtin_amdgcn_mfma_f32_16x16x32_bf16(kl0, qh[0], s[nt], 0, 0, 0);
            s[nt] = __builtin_amdgcn_mfma_f32_16x16x32_bf16(kl1, qh[1], s[nt], 0, 0, 0);
            s[nt] = __builtin_amdgcn_mfma_f32_16x16x32_bf16(kh0, ql[0], s[nt], 0, 0, 0);
            s[nt] = __builtin_amdgcn_mfma_f32_16x16x32_bf16(kh1, ql[1], s[nt], 0, 0, 0);
        }
        __builtin_amdgcn_s_setprio(0);

        // ---- online softmax: row t=lx lane-local across 4 quads ----
        const float m0q = fmaxf(fmaxf(s[0][0], s[0][1]), fmaxf(s[0][2], s[0][3]));
        const float m1q = fmaxf(fmaxf(s[1][0], s[1][1]), fmaxf(s[1][2], s[1][3]));
        const float m2q = fmaxf(fmaxf(s[2][0], s[2][1]), fmaxf(s[2][2], s[2][3]));
        const float m3q = fmaxf(fmaxf(s[3][0], s[3][1]), fmaxf(s[3][2], s[3][3]));
        float mt = fmaxf(fmaxf(m0q, m1q), fmaxf(m2q, m3q));
        mt = fmaxf(mt, __shfl_xor(mt, 16));
        mt = fmaxf(mt, __shfl_xor(mt, 32));

        // defer-max (T13): skip rescale while max grows <= 8 (exp2 domain,
        // P bounded by 2^8; fp32 accum + bf16 hi/lo keep precision)
        if (!__all(mt - mrun <= 8.0f)) {
            const float mnew  = fmaxf(mrun, mt);
            const float alpha = exp2_raw(mrun - mnew);
            mrun = mnew;
            lrun *= alpha;
            float ar[4];
#pragma unroll
            for (int r = 0; r < 4; ++r)
                ar[r] = __shfl(alpha, (ln & 48) | ((quad << 2) + r));
#pragma unroll
            for (int nt = 0; nt < 4; ++nt)
#pragma unroll
                for (int r = 0; r < 4; ++r) o[nt][r] *= ar[r];
        }

        float lt = 0.f;
#pragma unroll
        for (int nt = 0; nt < 4; ++nt)
#pragma unroll
            for (int r = 0; r < 4; ++r) {
                s[nt][r] = exp2_raw(s[nt][r] - mrun);
                lt += s[nt][r];
            }
        lt += __shfl_xor(lt, 16);
        lt += __shfl_xor(lt, 32);
        lrun += lt;

        // ---- pack P -> bf16 hi/lo A-fragments, fully in-register ----
        unsigned wh[4][2], wl[4][2];
#pragma unroll
        for (int nt = 0; nt < 4; ++nt) {
            wh[nt][0] = cvtpk_bf16(s[nt][0], s[nt][1]);
            wh[nt][1] = cvtpk_bf16(s[nt][2], s[nt][3]);
            const float h0 = bitsf(wh[nt][0] << 16);
            const float h1 = bitsf(wh[nt][0] & 0xffff0000u);
            const float h2 = bitsf(wh[nt][1] << 16);
            const float h3 = bitsf(wh[nt][1] & 0xffff0000u);
            wl[nt][0] = cvtpk_bf16(s[nt][0] - h0, s[nt][1] - h1);
            wl[nt][1] = cvtpk_bf16(s[nt][2] - h2, s[nt][3] - h3);
        }
        union PU { unsigned u[4]; bf16x8 v; };
        const PU ph0 = {{wh[0][0], wh[0][1], wh[1][0], wh[1][1]}};   // k 0..31
        const PU ph1 = {{wh[2][0], wh[2][1], wh[3][0], wh[3][1]}};   // k 32..63
        const PU pl0 = {{wl[0][0], wl[0][1], wl[1][0], wl[1][1]}};
        const PU pl1 = {{wl[2][0], wl[2][1], wl[3][0], wl[3][1]}};

        // ---- PV ----
        __builtin_amdgcn_s_setprio(1);
#pragma unroll
        for (int nt = 0; nt < 4; ++nt) {
            const int v0 = va0 + (nt << 10);
            const bf16x8 vh0 = *(const bf16x8*)&VH[v0];
            const bf16x8 vh1 = *(const bf16x8*)&VH[v0 ^ 32];
            const bf16x8 vl0 = *(const bf16x8*)&VL[v0];
            const bf16x8 vl1 = *(const bf16x8*)&VL[v0 ^ 32];
            o[nt] = __builtin_amdgcn_mfma_f32_16x16x32_bf16(ph0.v, vh0, o[nt], 0, 0, 0);
            o[nt] = __builtin_amdgcn_mfma_f32_16x16x32_bf16(ph1.v, vh1, o[nt], 0, 0, 0);
            o[nt] = __builtin_amdgcn_mfma_f32_16x16x32_bf16(pl0.v, vh0, o[nt], 0, 0, 0);
            o[nt] = __builtin_amdgcn_mfma_f32_16x16x32_bf16(pl1.v, vh1, o[nt], 0, 0, 0);
            o[nt] = __builtin_amdgcn_mfma_f32_16x16x32_bf16(ph0.v, vl0, o[nt], 0, 0, 0);
            o[nt] = __builtin_amdgcn_mfma_f32_16x16x32_bf16(ph1.v, vl1, o[nt], 0, 0, 0);
        }
        __builtin_amdgcn_s_setprio(0);

        __syncthreads();
        *(bf16x8*)&KH[lw] = rkh;
        *(bf16x8*)&KL[lw] = rkl;
        *(bf16x8*)&VH[lw] = rvh;
        *(bf16x8*)&VL[lw] = rvl;
        __syncthreads();
    }

    // ---- normalize + fused bf16 hi/lo store to AOh/AOl[b][t][h*64+dv] ----
    const float linv = 1.0f / lrun;
    float ir[4];
#pragma unroll
    for (int r = 0; r < 4; ++r)
        ir[r] = __shfl(linv, (ln & 48) | ((quad << 2) + r));
#pragma unroll
    for (int nt = 0; nt < 4; ++nt)
#pragma unroll
        for (int r = 0; r < 4; ++r) {
            const int t = qrow0 + quad*4 + r;
            const float res = o[nt][r] * ir[r];
            const unsigned u32 = fbits(res);
            const size_t off = (((size_t)b)*T_SEQ + t)*DM + h*HD + nt*16 + lx;
            AOh[off] = (ushort_t)(u32 >> 16);
            AOl[off] = f2bf(res - bitsf(u32 & 0xffff0000u));
        }
}

// -------------------------------------------------------------------------
// Memory plan: d_ws 128.03 MiB + d_out as scratch.
//   d_ws: Qhi Qlo Khi Klo Vthi Vtlo (6x16 MiB) | MSK 32 KiB |
//         32-MiB region: WqkvTh/Tl (12 MiB, dead after QKV GEMM) then
//         AOh/AOl (2x16 MiB, written by attention epilogue)
//   d_out: TokH/TokL (32 MiB) — dead after QKV GEMM
//   WoutTh/Tl <- Khi region (dead after attention)
// -------------------------------------------------------------------------
extern "C" void kernel_launch(void* const* d_in, const int* in_sizes, int n_in,
                              void* d_out, int out_size, void* d_ws, size_t ws_size,
                              hipStream_t stream)
{
    const float* tokens = (const float*)d_in[0];
    const int*   pad    = (const int*)d_in[1];
    const float* Wqkv   = (const float*)d_in[2];
    const float* bqkv   = (const float*)d_in[3];
    const float* Wout   = (const float*)d_in[4];
    const float* bout   = (const float*)d_in[5];
    float* out = (float*)d_out;

    const size_t SZ = (size_t)8388608;
    ushort_t* U = (ushort_t*)d_ws;
    ushort_t* Qhi  = U;
    ushort_t* Qlo  = U + SZ;
    ushort_t* Khi  = U + 2*SZ;
    ushort_t* Klo  = U + 3*SZ;
    ushort_t* Vthi = U + 4*SZ;
    ushort_t* Vtlo = U + 5*SZ;
    float* MSK = (float*)(U + 6*SZ);
    ushort_t* R   = (ushort_t*)(MSK + 8192);       // 32-MiB region
    ushort_t* WqkvTh = R;
    ushort_t* WqkvTl = R + (size_t)3*DM*DM;
    ushort_t* AOh = R;                             // overlays dead WqkvT
    ushort_t* AOl = R + SZ;
    ushort_t* TokH = (ushort_t*)d_out;             // scratch in d_out
    ushort_t* TokL = TokH + SZ;
    ushort_t* WoutTh = Khi;                        // dead after attention
    ushort_t* WoutTl = Khi + (size_t)DM*DM;

    maskprep_kernel<<<dim3(BATCH), dim3(256), 0, stream>>>(pad, MSK);
    split_kernel<<<dim3(8192), dim3(256), 0, stream>>>(tokens, TokH, TokL);
    transpose_split_kernel<<<dim3(48, 16), dim3(256), 0, stream>>>(
        Wqkv, WqkvTh, WqkvTl, DM, 3*DM);
    mfma_gemm_kernel<1><<<dim3(24, 128), dim3(256), 0, stream>>>(
        TokH, TokL, WqkvTh, WqkvTl, bqkv, nullptr,
        Qhi, Qlo, Khi, Klo, Vthi, Vtlo, BATCH*T_SEQ, 3*DM, DM);
    attn_mfma_kernel<<<dim3(1024), dim3(512), 0, stream>>>(
        Qhi, Qlo, Khi, Klo, Vthi, Vtlo, MSK, AOh, AOl);
    transpose_split_kernel<<<dim3(16, 16), dim3(256), 0, stream>>>(
        Wout, WoutTh, WoutTl, DM, DM);
    mfma_gemm_kernel<0><<<dim3(8, 128), dim3(256), 0, stream>>>(
        AOh, AOl, WoutTh, WoutTl, bout, out,
        nullptr, nullptr, nullptr, nullptr, nullptr, nullptr, BATCH*T_SEQ, DM, DM);
}

// Round 4
// 484.648 us; speedup vs baseline: 1.1722x; 1.1722x over previous
//
#include <hip/hip_runtime.h>
#include <cmath>

#define T_SEQ 2048
#define NH    16
#define HD    64
#define DM    1024
#define BATCH 4

typedef __attribute__((ext_vector_type(8))) short s16x8;
typedef __attribute__((ext_vector_type(8))) _Float16 f16x8;
typedef __attribute__((ext_vector_type(4))) float f32x4;
typedef unsigned short ushort_t;

__device__ __forceinline__ ushort_t f2h(float x) {   // rne fp32->fp16
    union { _Float16 h; ushort_t u; } v; v.h = (_Float16)x; return v.u;
}
__device__ __forceinline__ float h2f(ushort_t u) {
    union { ushort_t u; _Float16 h; } v; v.u = u; return (float)v.h;
}
// raw v_exp_f32 (2^x) — __exp2f doesn't exist on this ROCm (R10 compile fail)
__device__ __forceinline__ float exp2_raw(float x) {
    return __builtin_amdgcn_exp2f(x);
}

// async global->LDS DMA, 16 B per lane (verified R7/R9).
__device__ __forceinline__ void dma16(const void* g, const void* l) {
    __builtin_amdgcn_global_load_lds(
        (const __attribute__((address_space(1))) unsigned int*)(unsigned long long)g,
        (__attribute__((address_space(3))) unsigned int*)(unsigned int)(unsigned long long)l,
        16, 0, 0);
}

// -------------------------------------------------------------------------
// Kernel 1: mask prep. Emits ADDITIVE bias: 0.0 (attend) / -1e30 (pad).
// -------------------------------------------------------------------------
__global__ void maskprep_kernel(const int* __restrict__ pad, float* __restrict__ valid)
{
    __shared__ int sall[256];
    const int b = blockIdx.x;
    const int t = threadIdx.x;
    int allp = 1;
    for (int i = t; i < T_SEQ; i += 256) allp &= (pad[b*T_SEQ + i] != 0) ? 1 : 0;
    sall[t] = allp;
    __syncthreads();
    for (int s = 128; s > 0; s >>= 1) {
        if (t < s) sall[t] &= sall[t + s];
        __syncthreads();
    }
    const int ap = sall[0];
    for (int i = t; i < T_SEQ; i += 256) {
        const int p = (pad[b*T_SEQ + i] != 0) ? 1 : 0;
        valid[b*T_SEQ + i] = (p && !ap) ? -1e30f : 0.0f;
    }
}

// -------------------------------------------------------------------------
// Kernel 2: weight transpose+split. W[K][N] -> Th/Tl[N][K] as fp16 hi/lo
// of (32*w) — scaling keeps the lo part out of fp16 subnormal range
// (w sigma=1/32 -> lo ~1.5e-5 subnormal; 32w sigma=1 -> lo ~5e-4 normal).
// GEMM epilogue multiplies acc by 1/32.
// -------------------------------------------------------------------------
__global__ __launch_bounds__(256)
void transpose_split_kernel(const float* __restrict__ W,
                            ushort_t* __restrict__ Th, ushort_t* __restrict__ Tl,
                            int K, int N)
{
    __shared__ float T[64][68];
    const int tid = threadIdx.x;
    const int n0 = blockIdx.x * 64;
    const int k0 = blockIdx.y * 64;
#pragma unroll
    for (int i = 0; i < 4; ++i) {
        const int kr = (tid >> 4) + i*16;
        const int nc = (tid & 15) * 4;
        const float4 v = *(const float4*)&W[(size_t)(k0 + kr)*N + n0 + nc];
        T[nc+0][kr] = v.x; T[nc+1][kr] = v.y; T[nc+2][kr] = v.z; T[nc+3][kr] = v.w;
    }
    __syncthreads();
#pragma unroll
    for (int i = 0; i < 4; ++i) {
        const int nr = (tid >> 4) + i*16;
        const int kc = (tid & 15) * 4;
        ushort_t h[4], l[4];
#pragma unroll
        for (int j = 0; j < 4; ++j) {
            const float x = T[nr][kc + j] * 32.0f;
            h[j] = f2h(x);
            l[j] = f2h(x - h2f(h[j]));
        }
        const size_t off = (size_t)(n0 + nr)*K + k0 + kc;
        *(short4*)&Th[off] = make_short4((short)h[0], (short)h[1], (short)h[2], (short)h[3]);
        *(short4*)&Tl[off] = make_short4((short)l[0], (short)l[1], (short)l[2], (short)l[3]);
    }
}

// -------------------------------------------------------------------------
// Kernel 2b: row-major fp32 -> single fp16 (tokens).
// -------------------------------------------------------------------------
__global__ __launch_bounds__(256)
void split_kernel(const float* __restrict__ X, ushort_t* __restrict__ H)
{
    const int i = blockIdx.x * 256 + threadIdx.x;     // float4 index
    const float4 v = ((const float4*)X)[i];
    *(short4*)&H[(size_t)i*4] = make_short4(
        (short)f2h(v.x), (short)f2h(v.y), (short)f2h(v.z), (short)f2h(v.w));
}

// -------------------------------------------------------------------------
// Kernel 3/5: fp16 2-product MFMA GEMM. A = single fp16 activations,
// B = split fp16 hi/lo of 32*W. acc*(1/32)+bias in epilogue.
// 64x128xBK32 block tile, 32x64 wave tile, 16 MFMA per wave-K-step.
// -------------------------------------------------------------------------
template<int EPI>
__global__ __launch_bounds__(256)
void mfma_gemm_kernel(const ushort_t* __restrict__ Atf,
                      const ushort_t* __restrict__ BTh, const ushort_t* __restrict__ BTl,
                      const float* __restrict__ bias,
                      float* __restrict__ O0,
                      ushort_t* __restrict__ Qf,
                      ushort_t* __restrict__ Khf, ushort_t* __restrict__ Klf,
                      ushort_t* __restrict__ Vthf, ushort_t* __restrict__ Vtlf,
                      int M, int N, int K)
{
    __shared__ __align__(16) char smem[34816];
    char* smA  = smem;             // [64][32] fp16 = 4 KB
    char* smBh = smem + 4096;      // [128][32] fp16 = 8 KB
    char* smBl = smem + 12288;

    const int tid  = threadIdx.x;
    const int w    = tid >> 6;
    const int ln   = tid & 63;
    const int lx   = ln & 15;
    const int quad = ln >> 4;
    const int mw   = (w >> 1) * 32;
    const int nw   = (w & 1) * 64;
    const int m0   = blockIdx.y * 64;
    const int n0   = blockIdx.x * 128;

    const size_t gaA = (size_t)(m0 + w*16 + (ln >> 2))*K + (ln & 3)*8;
    const size_t gaB = (size_t)(n0 + w*32 + (ln >> 2))*K + (ln & 3)*8;
    const int ldsA = (w*64 + ln)*16;
    const int ldsB = (w*128 + ln)*16;

#define ISSUE_DMA(kk) do {                                               \
        dma16(Atf + gaA + (kk),        smA  + ldsA);                     \
        dma16(BTh + gaB + (kk),        smBh + ldsB);                     \
        dma16(BTh + gaB + 16*K + (kk), smBh + ldsB + 1024);              \
        dma16(BTl + gaB + (kk),        smBl + ldsB);                     \
        dma16(BTl + gaB + 16*K + (kk), smBl + ldsB + 1024);              \
    } while (0)

    f32x4 acc[2][4];
#pragma unroll
    for (int mt = 0; mt < 2; ++mt)
#pragma unroll
        for (int nt = 0; nt < 4; ++nt) acc[mt][nt] = (f32x4){0.f,0.f,0.f,0.f};

    ISSUE_DMA(0);

    for (int kk = 0; kk < K; kk += 32) {
        __syncthreads();

        f16x8 bfh[4], bfl[4];
#pragma unroll
        for (int nt = 0; nt < 4; ++nt) {
            const int off = (nw + nt*16 + lx)*64 + quad*16;
            bfh[nt] = *(const f16x8*)(smBh + off);
            bfl[nt] = *(const f16x8*)(smBl + off);
        }
        f16x8 af0, af1;
        {
            af0 = *(const f16x8*)(smA + (mw + lx)*64 + quad*16);
            af1 = *(const f16x8*)(smA + (mw + 16 + lx)*64 + quad*16);
        }
        __syncthreads();
        if (kk + 32 < K) ISSUE_DMA(kk + 32);

        __builtin_amdgcn_s_setprio(1);
#pragma unroll
        for (int nt = 0; nt < 4; ++nt) {
            acc[0][nt] = __builtin_amdgcn_mfma_f32_16x16x32_f16(af0, bfh[nt], acc[0][nt], 0, 0, 0);
            acc[0][nt] = __builtin_amdgcn_mfma_f32_16x16x32_f16(af0, bfl[nt], acc[0][nt], 0, 0, 0);
        }
#pragma unroll
        for (int nt = 0; nt < 4; ++nt) {
            acc[1][nt] = __builtin_amdgcn_mfma_f32_16x16x32_f16(af1, bfh[nt], acc[1][nt], 0, 0, 0);
            acc[1][nt] = __builtin_amdgcn_mfma_f32_16x16x32_f16(af1, bfl[nt], acc[1][nt], 0, 0, 0);
        }
        __builtin_amdgcn_s_setprio(0);
    }
#undef ISSUE_DMA

    const float INV32 = 0.03125f;
    // ---------------- epilogue ----------------
    if (EPI == 0) {
#pragma unroll
        for (int nt = 0; nt < 4; ++nt) {
            const int n = n0 + nw + nt*16 + lx;
#pragma unroll
            for (int mt = 0; mt < 2; ++mt)
#pragma unroll
                for (int r = 0; r < 4; ++r) {
                    const int m = m0 + mw + mt*16 + quad*4 + r;
                    O0[(size_t)m*N + n] = acc[mt][nt][r]*INV32 + bias[n];
                }
        }
    } else {
        const int which = n0 >> 10;           // block-uniform: 0=q 1=k 2=v
        const int hbase = (n0 & 1023) >> 6;
        const int b     = m0 >> 11;
        const int t0    = m0 & 2047;
        float* Ct = (float*)smem;             // Q/K: [64][132]; V: [128][68]
        const float ssign = (lx & 1) ? 1.0f : -1.0f;

        __syncthreads();
        if (which < 2) {
#pragma unroll
            for (int nt = 0; nt < 4; ++nt) {
                const int nl = nw + nt*16 + lx;
                const int d  = nl & 63;
                const float bn = bias[n0 + nl];
                const float freq = expf(-(float)(d >> 1) * 0.28782313662425575f);
#pragma unroll
                for (int mt = 0; mt < 2; ++mt)
#pragma unroll
                    for (int r = 0; r < 4; ++r) {
                        const int ml = mw + mt*16 + quad*4 + r;
                        const int t  = t0 + ml;
                        float res = acc[mt][nt][r]*INV32 + bn;
                        const float ang = (float)t * freq;
                        const float sn = sinf(ang), cs = cosf(ang);
                        const float prt = __shfl_xor(res, 1);
                        res = res*cs + ssign*prt*sn;
                        // Q scale folds 1/sqrt(hd) AND log2(e): softmax in exp2 domain
                        if (which == 0) res *= 0.18033688011112042f;
                        Ct[ml*132 + nl] = res;
                    }
            }
        } else {
#pragma unroll
            for (int nt = 0; nt < 4; ++nt) {
                const int nl = nw + nt*16 + lx;
                const float bn = bias[n0 + nl];
#pragma unroll
                for (int mt = 0; mt < 2; ++mt)
#pragma unroll
                    for (int r = 0; r < 4; ++r) {
                        const int ml = mw + mt*16 + quad*4 + r;
                        Ct[nl*68 + ml] = acc[mt][nt][r]*INV32 + bn;
                    }
            }
        }
        __syncthreads();

        if (which < 2) {
#pragma unroll
            for (int u = 0; u < 4; ++u) {
                const int L  = u*32 + (tid >> 3);
                const int t  = L & 63;
                const int hl = L >> 6;
                const int dg = (tid & 7) * 8;
                const float* src = &Ct[t*132 + hl*64 + dg];
                float v[8];
                *(f32x4*)&v[0] = *(const f32x4*)src;
                *(f32x4*)&v[4] = *(const f32x4*)(src + 4);
                const int bh = b*NH + hbase + hl;
                const size_t off = (((size_t)bh)*T_SEQ + t0 + t)*64 + dg;
                s16x8 h8;
#pragma unroll
                for (int j = 0; j < 8; ++j) h8[j] = (short)f2h(v[j]);
                if (which == 0) {
                    *(s16x8*)&Qf[off] = h8;
                } else {
                    s16x8 l8;
#pragma unroll
                    for (int j = 0; j < 8; ++j)
                        l8[j] = (short)f2h(v[j] - h2f((ushort_t)h8[j]));
                    *(s16x8*)&Khf[off] = h8;
                    *(s16x8*)&Klf[off] = l8;
                }
            }
        } else {
#pragma unroll
            for (int u = 0; u < 4; ++u) {
                const int row = u*32 + (tid >> 3);
                const int d   = row & 63;
                const int hl  = row >> 6;
                const int tg  = (tid & 7) * 8;
                const float* src = &Ct[row*68 + tg];
                float v[8];
                *(f32x4*)&v[0] = *(const f32x4*)src;
                *(f32x4*)&v[4] = *(const f32x4*)(src + 4);
                s16x8 h8, l8;
#pragma unroll
                for (int j = 0; j < 8; ++j) {
                    h8[j] = (short)f2h(v[j]);
                    l8[j] = (short)f2h(v[j] - h2f((ushort_t)h8[j]));
                }
                const int bh = b*NH + hbase + hl;
                const size_t off = (((size_t)bh)*HD + d)*T_SEQ + t0 + tg;
                *(s16x8*)&Vthf[off] = h8;
                *(s16x8*)&Vtlf[off] = l8;
            }
        }
    }
}

// -------------------------------------------------------------------------
// Kernel 4: flash attention, swapped-QK^T (R1 layout), fp16 2-product:
// K/V split fp16 hi/lo (22-bit), Q and P single fp16. 32 MFMA/tile (was 48).
// Mask folded into MFMA C-in, defer-max (THR=8), s_setprio (T5).
// -------------------------------------------------------------------------
__global__ __launch_bounds__(512, 4)
void attn_mfma_kernel(const ushort_t* __restrict__ Qf,
                      const ushort_t* __restrict__ Khf, const ushort_t* __restrict__ Klf,
                      const ushort_t* __restrict__ Vthf, const ushort_t* __restrict__ Vtlf,
                      const float* __restrict__ mbias,
                      ushort_t* __restrict__ AOf)
{
    __shared__ ushort_t KH[64*64];
    __shared__ ushort_t KL[64*64];
    __shared__ ushort_t VH[64*64];
    __shared__ ushort_t VL[64*64];

    const int tid  = threadIdx.x;
    const int w    = tid >> 6;          // 0..7
    const int ln   = tid & 63;
    const int lx   = ln & 15;
    const int quad = ln >> 4;

    // 1024 blocks: id&7 = bh low bits (XCD), (id>>3)&15 = qt, id>>7 = bh hi
    const int id = blockIdx.x;
    const int qt = (id >> 3) & 15;
    const int bh = ((id >> 7) << 3) | (id & 7);
    const int b  = bh >> 4;
    const int h  = bh & 15;
    const int qrow0 = qt*128 + w*16;

    // Q fragments (B operand, single fp16)
    f16x8 qf0, qf1;
    {
        const size_t qoff = (((size_t)bh)*T_SEQ + qrow0 + lx)*HD + quad*8;
        qf0 = *(const f16x8*)&Qf[qoff];
        qf1 = *(const f16x8*)&Qf[qoff + 32];
    }

    // staging: wave w stages rows [w*8, w*8+8); lane ln -> row w*8+(ln>>3),
    // chunk ln&7; swizzled store pos = sch ^ g(srow).
    const int srow = w*8 + (ln >> 3);
    const int sch  = ln & 7;
    const size_t kg0 = ((size_t)bh*T_SEQ + srow)*HD + sch*8;
    const size_t vg0 = ((size_t)bh*HD + srow)*T_SEQ + sch*8;
    const int gs = ((ln >> 3) & 3) ^ ((w & 1) << 2);
    const int lw = srow*64 + ((sch ^ gs) << 3);

    // K A-fragment read base: row(nt=0) = 8*(lx>>2)+(lx&3); g(row) == lx&7
    const int r0  = ((lx >> 2) << 3) + (lx & 3);
    const int ka0 = r0*64 + ((quad ^ (lx & 7)) << 3);
    // V B-fragment read base: row = nt*16+lx; g(row) == gv
    const int gv  = (lx & 3) ^ (((lx >> 3) & 1) << 2);
    const int va0 = lx*64 + ((quad ^ gv) << 3);

    // additive mask bias, float4 per (nt): k = kt*64 +32*(nt>>1)+8*quad+4*(nt&1)+r
    const float* mrow = mbias + (size_t)b*T_SEQ + (quad << 3);

    f32x4 o[4];
#pragma unroll
    for (int nt = 0; nt < 4; ++nt) o[nt] = (f32x4){0.f, 0.f, 0.f, 0.f};
    float mrun = -INFINITY;
    float lrun = 0.f;

    s16x8 rkh, rkl, rvh, rvl;
    rkh = *(const s16x8*)&Khf [kg0];
    rkl = *(const s16x8*)&Klf [kg0];
    rvh = *(const s16x8*)&Vthf[vg0];
    rvl = *(const s16x8*)&Vtlf[vg0];
    *(s16x8*)&KH[lw] = rkh;
    *(s16x8*)&KL[lw] = rkl;
    *(s16x8*)&VH[lw] = rvh;
    *(s16x8*)&VL[lw] = rvl;
    __syncthreads();

    for (int kt = 0; kt < T_SEQ/64; ++kt) {
        const int ktn = (kt+1 < T_SEQ/64) ? kt+1 : kt;
        rkh = *(const s16x8*)&Khf [kg0 + (size_t)ktn*64*HD];
        rkl = *(const s16x8*)&Klf [kg0 + (size_t)ktn*64*HD];
        rvh = *(const s16x8*)&Vthf[vg0 + ktn*64];
        rvl = *(const s16x8*)&Vtlf[vg0 + ktn*64];

        // ---- QK^T (K split fp16 is the A operand; mask bias as C-in) ----
        f32x4 s[4];
        __builtin_amdgcn_s_setprio(1);
#pragma unroll
        for (int nt = 0; nt < 4; ++nt) {
            const int a0 = ka0 + ((nt & 1) << 8) + ((nt >> 1) << 11);
            const f16x8 kh0 = *(const f16x8*)&KH[a0];
            const f16x8 kh1 = *(const f16x8*)&KH[a0 ^ 32];
            const f16x8 kl0 = *(const f16x8*)&KL[a0];
            const f16x8 kl1 = *(const f16x8*)&KL[a0 ^ 32];
            s[nt] = *(const f32x4*)&mrow[kt*64 + ((nt >> 1) << 5) + ((nt & 1) << 2)];
            s[nt] = __builtin_amdgcn_mfma_f32_16x16x32_f16(kh0, qf0, s[nt], 0, 0, 0);
            s[nt] = __builtin_amdgcn_mfma_f32_16x16x32_f16(kh1, qf1, s[nt], 0, 0, 0);
            s[nt] = __builtin_amdgcn_mfma_f32_16x16x32_f16(kl0, qf0, s[nt], 0, 0, 0);
            s[nt] = __builtin_amdgcn_mfma_f32_16x16x32_f16(kl1, qf1, s[nt], 0, 0, 0);
        }
        __builtin_amdgcn_s_setprio(0);

        // ---- online softmax: row t=lx lane-local across 4 quads ----
        const float m0q = fmaxf(fmaxf(s[0][0], s[0][1]), fmaxf(s[0][2], s[0][3]));
        const float m1q = fmaxf(fmaxf(s[1][0], s[1][1]), fmaxf(s[1][2], s[1][3]));
        const float m2q = fmaxf(fmaxf(s[2][0], s[2][1]), fmaxf(s[2][2], s[2][3]));
        const float m3q = fmaxf(fmaxf(s[3][0], s[3][1]), fmaxf(s[3][2], s[3][3]));
        float mt = fmaxf(fmaxf(m0q, m1q), fmaxf(m2q, m3q));
        mt = fmaxf(mt, __shfl_xor(mt, 16));
        mt = fmaxf(mt, __shfl_xor(mt, 32));

        // defer-max (T13): skip rescale while max grows <= 8 (exp2 domain)
        if (!__all(mt - mrun <= 8.0f)) {
            const float mnew  = fmaxf(mrun, mt);
            const float alpha = exp2_raw(mrun - mnew);
            mrun = mnew;
            lrun *= alpha;
            float ar[4];
#pragma unroll
            for (int r = 0; r < 4; ++r)
                ar[r] = __shfl(alpha, (ln & 48) | ((quad << 2) + r));
#pragma unroll
            for (int nt = 0; nt < 4; ++nt)
#pragma unroll
                for (int r = 0; r < 4; ++r) o[nt][r] *= ar[r];
        }

        float lt = 0.f;
#pragma unroll
        for (int nt = 0; nt < 4; ++nt)
#pragma unroll
            for (int r = 0; r < 4; ++r) {
                s[nt][r] = exp2_raw(s[nt][r] - mrun);
                lt += s[nt][r];
            }
        lt += __shfl_xor(lt, 16);
        lt += __shfl_xor(lt, 32);
        lrun += lt;

        // ---- pack P -> single fp16 A-fragments (RNE), in-register ----
        unsigned pw[4][2];
#pragma unroll
        for (int nt = 0; nt < 4; ++nt) {
            pw[nt][0] = (unsigned)f2h(s[nt][0]) | ((unsigned)f2h(s[nt][1]) << 16);
            pw[nt][1] = (unsigned)f2h(s[nt][2]) | ((unsigned)f2h(s[nt][3]) << 16);
        }
        union PU { unsigned u[4]; f16x8 v; };
        const PU pf0 = {{pw[0][0], pw[0][1], pw[1][0], pw[1][1]}};   // k 0..31
        const PU pf1 = {{pw[2][0], pw[2][1], pw[3][0], pw[3][1]}};   // k 32..63

        // ---- PV (V split fp16 hi/lo) ----
        __builtin_amdgcn_s_setprio(1);
#pragma unroll
        for (int nt = 0; nt < 4; ++nt) {
            const int v0 = va0 + (nt << 10);
            const f16x8 vh0 = *(const f16x8*)&VH[v0];
            const f16x8 vh1 = *(const f16x8*)&VH[v0 ^ 32];
            const f16x8 vl0 = *(const f16x8*)&VL[v0];
            const f16x8 vl1 = *(const f16x8*)&VL[v0 ^ 32];
            o[nt] = __builtin_amdgcn_mfma_f32_16x16x32_f16(pf0.v, vh0, o[nt], 0, 0, 0);
            o[nt] = __builtin_amdgcn_mfma_f32_16x16x32_f16(pf1.v, vh1, o[nt], 0, 0, 0);
            o[nt] = __builtin_amdgcn_mfma_f32_16x16x32_f16(pf0.v, vl0, o[nt], 0, 0, 0);
            o[nt] = __builtin_amdgcn_mfma_f32_16x16x32_f16(pf1.v, vl1, o[nt], 0, 0, 0);
        }
        __builtin_amdgcn_s_setprio(0);

        __syncthreads();
        *(s16x8*)&KH[lw] = rkh;
        *(s16x8*)&KL[lw] = rkl;
        *(s16x8*)&VH[lw] = rvh;
        *(s16x8*)&VL[lw] = rvl;
        __syncthreads();
    }

    // ---- normalize + single fp16 store to AOf[b][t][h*64+dv] ----
    const float linv = 1.0f / lrun;
    float ir[4];
#pragma unroll
    for (int r = 0; r < 4; ++r)
        ir[r] = __shfl(linv, (ln & 48) | ((quad << 2) + r));
#pragma unroll
    for (int nt = 0; nt < 4; ++nt)
#pragma unroll
        for (int r = 0; r < 4; ++r) {
            const int t = qrow0 + quad*4 + r;
            const float res = o[nt][r] * ir[r];
            const size_t off = (((size_t)b)*T_SEQ + t)*DM + h*HD + nt*16 + lx;
            AOf[off] = f2h(res);
        }
}

// -------------------------------------------------------------------------
// Memory plan: d_ws 128.03 MiB + d_out as scratch.
//   d_ws slots (16 MiB each): Qf | Khf | Klf | Vthf | Vtlf | (free) |
//         MSK 32 KiB | 32-MiB region R: WqkvTh/Tl (12 MiB, dead after
//         QKV GEMM) then AOf (16 MiB, attention output)
//   d_out: TokF (16 MiB) — dead after QKV GEMM
//   WoutTh/Tl <- Khf slot (dead after attention)
// -------------------------------------------------------------------------
extern "C" void kernel_launch(void* const* d_in, const int* in_sizes, int n_in,
                              void* d_out, int out_size, void* d_ws, size_t ws_size,
                              hipStream_t stream)
{
    const float* tokens = (const float*)d_in[0];
    const int*   pad    = (const int*)d_in[1];
    const float* Wqkv   = (const float*)d_in[2];
    const float* bqkv   = (const float*)d_in[3];
    const float* Wout   = (const float*)d_in[4];
    const float* bout   = (const float*)d_in[5];
    float* out = (float*)d_out;

    const size_t SZ = (size_t)8388608;
    ushort_t* U = (ushort_t*)d_ws;
    ushort_t* Qf   = U;
    ushort_t* Khf  = U + SZ;
    ushort_t* Klf  = U + 2*SZ;
    ushort_t* Vthf = U + 3*SZ;
    ushort_t* Vtlf = U + 4*SZ;
    float* MSK = (float*)(U + 6*SZ);
    ushort_t* R   = (ushort_t*)(MSK + 8192);       // 32-MiB region
    ushort_t* WqkvTh = R;
    ushort_t* WqkvTl = R + (size_t)3*DM*DM;
    ushort_t* AOf = R;                             // overlays dead WqkvT
    ushort_t* TokF = (ushort_t*)d_out;             // scratch in d_out
    ushort_t* WoutTh = Khf;                        // dead after attention
    ushort_t* WoutTl = Khf + (size_t)DM*DM;

    maskprep_kernel<<<dim3(BATCH), dim3(256), 0, stream>>>(pad, MSK);
    split_kernel<<<dim3(8192), dim3(256), 0, stream>>>(tokens, TokF);
    transpose_split_kernel<<<dim3(48, 16), dim3(256), 0, stream>>>(
        Wqkv, WqkvTh, WqkvTl, DM, 3*DM);
    mfma_gemm_kernel<1><<<dim3(24, 128), dim3(256), 0, stream>>>(
        TokF, WqkvTh, WqkvTl, bqkv, nullptr,
        Qf, Khf, Klf, Vthf, Vtlf, BATCH*T_SEQ, 3*DM, DM);
    attn_mfma_kernel<<<dim3(1024), dim3(512), 0, stream>>>(
        Qf, Khf, Klf, Vthf, Vtlf, MSK, AOf);
    transpose_split_kernel<<<dim3(16, 16), dim3(256), 0, stream>>>(
        Wout, WoutTh, WoutTl, DM, DM);
    mfma_gemm_kernel<0><<<dim3(8, 128), dim3(256), 0, stream>>>(
        AOf, WoutTh, WoutTl, bout, out,
        nullptr, nullptr, nullptr, nullptr, nullptr, BATCH*T_SEQ, DM, DM);
}